// Round 1
// baseline (203.925 us; speedup 1.0000x reference)
//
#include <hip/hip_runtime.h>
#include <math.h>

// Problem constants (B,H,W,C = 4,384,384,48; KERNEL=3 -> R=Cc=128)
#define CC_CH   48          // channels
#define ROWS    128         // output rows (= cols)
#define ROW_STRIDE 18432    // 384*48 floats per input image row
#define TOTAL   (4*128*128*48)   // 3,145,728 output elements
#define EPS     1e-4f

__global__ __launch_bounds__(256) void fuzzy_pool_kernel(
        const float* __restrict__ x, float* __restrict__ out) {
    const int F = blockIdx.x * 256 + threadIdx.x;
    if (F >= TOTAL) return;

    // F = ((b*128 + r)*128 + cc)*48 + g
    const int g  = F % 48;
    const int P  = F / 48;
    const int cc = P & 127;
    const int r  = (P >> 7) & 127;
    const int b  = P >> 14;

    // 9 consecutive floats in one input row
    const int kr = g >> 4;              // which of the 3 kernel rows
    const int o  = (g & 15) * 9;        // offset within the 144-float row span
    const float* __restrict__ p =
        x + ((size_t)(b * 384 + 3 * r + kr) * ROW_STRIDE + cc * 144 + o);

    float v[9];
#pragma unroll
    for (int t = 0; t < 9; ++t) v[t] = p[t];

    // ---- membership(x): kmm = [m(1:8), m(2:7), m(3:6), x4, m(0:9)] ----
    float s9 = 0.f;
#pragma unroll
    for (int t = 0; t < 9; ++t) s9 += v[t];
    const float m9 = s9 / 9.0f;
    const float m7 = (v[1] + v[2] + v[3] + v[4] + v[5] + v[6] + v[7]) / 7.0f;
    const float m5 = (v[2] + v[3] + v[4] + v[5] + v[6]) / 5.0f;
    const float m3 = (v[3] + v[4] + v[5]) / 3.0f;

    float kmm[5];
    kmm[0] = m7; kmm[1] = m5; kmm[2] = m3; kmm[3] = v[4]; kmm[4] = m9;

    const float v_avg = (kmm[0] + kmm[1] + kmm[2] + kmm[3] + kmm[4]) / 5.0f;

    // ---- omega = |x - v_avg|; var = membership(omega) + eps ----
    float w[9];
#pragma unroll
    for (int t = 0; t < 9; ++t) w[t] = fabsf(v[t] - v_avg);

    float ws9 = 0.f;
#pragma unroll
    for (int t = 0; t < 9; ++t) ws9 += w[t];

    float var[5];
    var[0] = (w[1] + w[2] + w[3] + w[4] + w[5] + w[6] + w[7]) / 7.0f + EPS;
    var[1] = (w[2] + w[3] + w[4] + w[5] + w[6]) / 5.0f + EPS;
    var[2] = (w[3] + w[4] + w[5]) / 3.0f + EPS;
    var[3] = w[4] + EPS;
    var[4] = ws9 / 9.0f + EPS;

    float inv[5];
#pragma unroll
    for (int j = 0; j < 5; ++j) inv[j] = 1.0f / var[j];

    // ---- pi[j][t] = exp(-0.5*(x_t-kmm_j)^2 / var_j); reduce over j ----
    float sum_pi[9];
    float max_pi[9];
#pragma unroll
    for (int t = 0; t < 9; ++t) { sum_pi[t] = 0.f; max_pi[t] = 0.f; }

#pragma unroll
    for (int j = 0; j < 5; ++j) {
        const float k  = kmm[j];
        const float iv = inv[j];
#pragma unroll
        for (int t = 0; t < 9; ++t) {
            const float d  = v[t] - k;
            const float pi = expf(((-0.5f * d) * d) * iv);
            sum_pi[t] += pi;
            max_pi[t] = fmaxf(max_pi[t], pi);   // pi > 0 always
        }
    }

    float avg_pi[9];
#pragma unroll
    for (int t = 0; t < 9; ++t) avg_pi[t] = sum_pi[t] * 0.2f;

    float thresh = max_pi[0];
#pragma unroll
    for (int t = 1; t < 9; ++t) thresh = fminf(thresh, max_pi[t]);

    bool m_mem = false;
#pragma unroll
    for (int t = 0; t < 9; ++t) m_mem = m_mem || (avg_pi[t] > thresh);

    float res;
    if (m_mem) {
        res = m9;                      // mean_x == mean of the 9 values
    } else if (var[4] < EPS) {         // m_only_var
        res = v_avg;
    } else {                           // m_unimp: weighted-average denoising
        float sn = 0.f, sd = 0.f;
#pragma unroll
        for (int t = 0; t < 9; ++t) { sn += avg_pi[t] * v[t]; sd += avg_pi[t]; }
        res = sn / sd;
    }

    out[F] = res;
}

extern "C" void kernel_launch(void* const* d_in, const int* in_sizes, int n_in,
                              void* d_out, int out_size, void* d_ws, size_t ws_size,
                              hipStream_t stream) {
    (void)in_sizes; (void)n_in; (void)d_ws; (void)ws_size; (void)out_size;
    const float* x = (const float*)d_in[0];
    float* out = (float*)d_out;
    const int blocks = (TOTAL + 255) / 256;   // 12288
    fuzzy_pool_kernel<<<blocks, 256, 0, stream>>>(x, out);
}

// Round 2
// 172.908 us; speedup vs baseline: 1.1794x; 1.1794x over previous
//
#include <hip/hip_runtime.h>
#include <math.h>

// Problem constants (B,H,W,C = 4,384,384,48; KERNEL=3 -> R=Cc=128)
#define ROW_STRIDE 18432    // 384*48 floats per input image row
#define TOTAL   (4*128*128*48)   // 3,145,728 output elements
#define EPS     1e-4f

__global__ __launch_bounds__(256) void fuzzy_pool_kernel(
        const float* __restrict__ x, float* __restrict__ out) {
    const int F = blockIdx.x * 256 + threadIdx.x;
    if (F >= TOTAL) return;

    // F = ((b*128 + r)*128 + cc)*48 + g
    const int g  = F % 48;
    const int P  = F / 48;
    const int cc = P & 127;
    const int r  = (P >> 7) & 127;
    const int b  = P >> 14;

    // 9 consecutive floats in one input row
    const int kr = g >> 4;              // which of the 3 kernel rows
    const int o  = (g & 15) * 9;        // offset within the 144-float row span
    const float* __restrict__ p =
        x + ((size_t)(b * 384 + 3 * r + kr) * ROW_STRIDE + cc * 144 + o);

    float v[9];
#pragma unroll
    for (int t = 0; t < 9; ++t) v[t] = p[t];

    // ---- membership(x): kmm = [m(1:8), m(2:7), m(3:6), x4, m(0:9)] ----
    float s9 = 0.f;
#pragma unroll
    for (int t = 0; t < 9; ++t) s9 += v[t];
    const float m9 = s9 / 9.0f;
    const float m7 = (v[1] + v[2] + v[3] + v[4] + v[5] + v[6] + v[7]) / 7.0f;
    const float m5 = (v[2] + v[3] + v[4] + v[5] + v[6]) / 5.0f;
    const float m3 = (v[3] + v[4] + v[5]) / 3.0f;

    float kmm[5];
    kmm[0] = m7; kmm[1] = m5; kmm[2] = m3; kmm[3] = v[4]; kmm[4] = m9;

    const float v_avg = (kmm[0] + kmm[1] + kmm[2] + kmm[3] + kmm[4]) / 5.0f;

    // ---- omega = |x - v_avg|; var = membership(omega) + eps ----
    float w[9];
#pragma unroll
    for (int t = 0; t < 9; ++t) w[t] = fabsf(v[t] - v_avg);

    float ws9 = 0.f;
#pragma unroll
    for (int t = 0; t < 9; ++t) ws9 += w[t];

    float var4;   // var[..., 4] = mean(omega) + eps  (the m_only_var probe)
    float c[5];   // c[j] = -0.5 / var[j]  (via 1-ulp v_rcp_f32)
    {
        const float va = (w[1] + w[2] + w[3] + w[4] + w[5] + w[6] + w[7]) / 7.0f + EPS;
        const float vb = (w[2] + w[3] + w[4] + w[5] + w[6]) / 5.0f + EPS;
        const float vc = (w[3] + w[4] + w[5]) / 3.0f + EPS;
        const float vd = w[4] + EPS;
        var4 = ws9 / 9.0f + EPS;
        c[0] = -0.5f * __builtin_amdgcn_rcpf(va);
        c[1] = -0.5f * __builtin_amdgcn_rcpf(vb);
        c[2] = -0.5f * __builtin_amdgcn_rcpf(vc);
        c[3] = -0.5f * __builtin_amdgcn_rcpf(vd);
        c[4] = -0.5f * __builtin_amdgcn_rcpf(var4);
    }

    // ---- pi[j][t] = exp(c_j * d^2); reduce over j (sum + max) ----
    float sum_pi[9];
    float max_pi[9];
#pragma unroll
    for (int t = 0; t < 9; ++t) { sum_pi[t] = 0.f; max_pi[t] = 0.f; }

#pragma unroll
    for (int j = 0; j < 5; ++j) {
        const float k  = kmm[j];
        const float cj = c[j];
#pragma unroll
        for (int t = 0; t < 9; ++t) {
            const float d  = v[t] - k;
            const float pi = __expf(cj * d * d);   // v_exp_f32, 1 ulp
            sum_pi[t] += pi;
            max_pi[t] = fmaxf(max_pi[t], pi);      // pi >= 0 always
        }
    }

    float avg_pi[9];
#pragma unroll
    for (int t = 0; t < 9; ++t) avg_pi[t] = sum_pi[t] * 0.2f;

    float thresh = max_pi[0];
#pragma unroll
    for (int t = 1; t < 9; ++t) thresh = fminf(thresh, max_pi[t]);

    bool m_mem = false;
#pragma unroll
    for (int t = 0; t < 9; ++t) m_mem = m_mem || (avg_pi[t] > thresh);

    float res;
    if (m_mem) {
        res = m9;                      // mean_x == mean of the 9 values
    } else if (var4 < EPS) {           // m_only_var
        res = v_avg;
    } else {                           // m_unimp: weighted-average denoising
        float sn = 0.f, sd = 0.f;
#pragma unroll
        for (int t = 0; t < 9; ++t) { sn += avg_pi[t] * v[t]; sd += avg_pi[t]; }
        res = sn * __builtin_amdgcn_rcpf(sd);
    }

    out[F] = res;
}

extern "C" void kernel_launch(void* const* d_in, const int* in_sizes, int n_in,
                              void* d_out, int out_size, void* d_ws, size_t ws_size,
                              hipStream_t stream) {
    (void)in_sizes; (void)n_in; (void)d_ws; (void)ws_size; (void)out_size;
    const float* x = (const float*)d_in[0];
    float* out = (float*)d_out;
    const int blocks = (TOTAL + 255) / 256;   // 12288
    fuzzy_pool_kernel<<<blocks, 256, 0, stream>>>(x, out);
}

// Round 3
// 169.539 us; speedup vs baseline: 1.2028x; 1.0199x over previous
//
#include <hip/hip_runtime.h>
#include <math.h>

// Problem constants (B,H,W,C = 4,384,384,48; KERNEL=3 -> R=Cc=128)
#define ROW_STRIDE 18432          // 384*48 floats per input image row
#define TOTAL    (4*128*128*48)   // 3,145,728 output elements
#define NTHREADS (TOTAL/4)        // 786,432 threads, 4 outputs each
#define EPS      1e-4f

static __device__ __forceinline__ float rcp_f(float a) {
    return __builtin_amdgcn_rcpf(a);      // v_rcp_f32, 1 ulp
}

__global__ __launch_bounds__(256) void fuzzy_pool_kernel(
        const float* __restrict__ x, float* __restrict__ out) {
    const int tid = blockIdx.x * 256 + threadIdx.x;   // one thread = 4 outputs

    // F0 = tid*4; g0 = F0 % 48; P = F0 / 48
    const int q  = tid / 12;              // P   (compiler: magic-mul)
    const int g4 = tid - q * 12;          // g0/4 in 0..11
    const int g0 = g4 * 4;
    const int cc = q & 127;
    const int r  = (q >> 7) & 127;
    const int b  = q >> 14;

    const int kr = g0 >> 4;               // kernel row (4-groups never straddle)
    const int o  = (g0 & 15) * 9;         // 0,36,72,108 floats -> 16B aligned

    const float4* __restrict__ p4 = (const float4*)(
        x + ((size_t)(b * 384 + 3 * r + kr) * ROW_STRIDE + cc * 144 + o));

    // 36 contiguous floats = the 4 groups' 9-vectors, via 9 dwordx4 loads
    float vv[36];
#pragma unroll
    for (int i = 0; i < 9; ++i) {
        const float4 t4 = p4[i];
        vv[4*i+0] = t4.x; vv[4*i+1] = t4.y; vv[4*i+2] = t4.z; vv[4*i+3] = t4.w;
    }

    const float R3 = 1.0f/3.0f, R5 = 0.2f, R7 = 1.0f/7.0f, R9 = 1.0f/9.0f;
    const float NC = -0.5f * 1.44269504088896340736f;   // -0.5*log2(e)

    float res[4];
#pragma unroll
    for (int gi = 0; gi < 4; ++gi) {
        const float* v = vv + gi * 9;

        // ---- membership(x): nested sums, CSE'd ----
        const float s3 = v[3] + v[4] + v[5];
        const float s5 = s3 + v[2] + v[6];
        const float s7 = s5 + v[1] + v[7];
        const float s9 = s7 + v[0] + v[8];
        const float m3 = s3 * R3, m5 = s5 * R5, m7 = s7 * R7, m9 = s9 * R9;

        float kmm[5];
        kmm[0] = m7; kmm[1] = m5; kmm[2] = m3; kmm[3] = v[4]; kmm[4] = m9;

        const float v_avg = (m7 + m5 + m3 + v[4] + m9) * R5;

        // ---- omega = |x - v_avg|; var = membership(omega) + eps ----
        float w[9];
#pragma unroll
        for (int t = 0; t < 9; ++t) w[t] = fabsf(v[t] - v_avg);

        const float t3 = w[3] + w[4] + w[5];
        const float t5 = t3 + w[2] + w[6];
        const float t7 = t5 + w[1] + w[7];
        const float t9 = t7 + w[0] + w[8];
        const float var4 = t9 * R9 + EPS;   // var[...,4] (m_only_var probe)

        float c[5];                          // c_j = -0.5*log2e / var_j
        c[0] = NC * rcp_f(t7 * R7 + EPS);
        c[1] = NC * rcp_f(t5 * R5 + EPS);
        c[2] = NC * rcp_f(t3 * R3 + EPS);
        c[3] = NC * rcp_f(w[4] + EPS);
        c[4] = NC * rcp_f(var4);

        // ---- pi[j][t] = 2^(c_j * d^2); reduce over j (sum + max) ----
        float sum_pi[9], max_pi[9];
#pragma unroll
        for (int t = 0; t < 9; ++t) { sum_pi[t] = 0.f; max_pi[t] = 0.f; }

#pragma unroll
        for (int j = 0; j < 5; ++j) {
            const float k  = kmm[j];
            const float cj = c[j];
#pragma unroll
            for (int t = 0; t < 9; ++t) {
                const float d  = v[t] - k;
                const float pi = __builtin_amdgcn_exp2f(cj * d * d); // v_exp_f32
                sum_pi[t] += pi;
                max_pi[t] = fmaxf(max_pi[t], pi);   // pi >= 0 always
            }
        }

        float thresh = fminf(fminf(max_pi[0], max_pi[1]), max_pi[2]);
        thresh = fminf(fminf(thresh, max_pi[3]), max_pi[4]);
        thresh = fminf(fminf(thresh, max_pi[5]), max_pi[6]);
        thresh = fminf(fminf(thresh, max_pi[7]), max_pi[8]);

        bool m_mem = false;
#pragma unroll
        for (int t = 0; t < 9; ++t) m_mem = m_mem || (sum_pi[t] * R5 > thresh);

        float r_out;
        if (m_mem) {
            r_out = m9;                    // mean of the 9 values
        } else if (var4 < EPS) {           // m_only_var
            r_out = v_avg;
        } else {                           // weighted-average denoising
            float sn = 0.f, sd = 0.f;
#pragma unroll
            for (int t = 0; t < 9; ++t) {
                const float a = sum_pi[t] * R5;
                sn += a * v[t]; sd += a;
            }
            r_out = sn * rcp_f(sd);
        }
        res[gi] = r_out;
    }

    float4 o4;
    o4.x = res[0]; o4.y = res[1]; o4.z = res[2]; o4.w = res[3];
    *(float4*)(out + (size_t)tid * 4) = o4;   // 16B-aligned (tid*4 % 4 == 0)
}

extern "C" void kernel_launch(void* const* d_in, const int* in_sizes, int n_in,
                              void* d_out, int out_size, void* d_ws, size_t ws_size,
                              hipStream_t stream) {
    (void)in_sizes; (void)n_in; (void)d_ws; (void)ws_size; (void)out_size;
    const float* x = (const float*)d_in[0];
    float* out = (float*)d_out;
    const int blocks = NTHREADS / 256;    // 3072, exact
    fuzzy_pool_kernel<<<blocks, 256, 0, stream>>>(x, out);
}

// Round 4
// 169.266 us; speedup vs baseline: 1.2048x; 1.0016x over previous
//
#include <hip/hip_runtime.h>
#include <math.h>

// Problem constants (B,H,W,C = 4,384,384,48; KERNEL=3 -> R=Cc=128)
#define ROW_STRIDE 18432          // 384*48 floats per input image row
#define TOTAL    (4*128*128*48)   // 3,145,728 output elements (grid exact)
#define EPS      1e-4f

static __device__ __forceinline__ float rcp_f(float a) {
    return __builtin_amdgcn_rcpf(a);      // v_rcp_f32, 1 ulp
}

// waves_per_eu(2,4): tell the register allocator 4 waves/EU occupancy is
// enough -> ~128-VGPR budget, keep v/w/sum/max/kmm/c all live (R1/R2 showed
// VGPR_Count=32 for >=45 live floats => remat/spill churn inflating VALU).
__global__ __launch_bounds__(256)
__attribute__((amdgpu_waves_per_eu(2, 4)))
void fuzzy_pool_kernel(const float* __restrict__ x, float* __restrict__ out) {
    const int F = blockIdx.x * 256 + threadIdx.x;   // grid is exact, no guard

    // F = ((b*128 + r)*128 + cc)*48 + g
    const int g  = F % 48;
    const int P  = F / 48;
    const int cc = P & 127;
    const int r  = (P >> 7) & 127;
    const int b  = P >> 14;

    // 9 consecutive floats in one input row
    const int kr = g >> 4;              // kernel row
    const int o  = (g & 15) * 9;        // float offset within 144-float span
    const float* __restrict__ p =
        x + ((size_t)(b * 384 + 3 * r + kr) * ROW_STRIDE + cc * 144 + o);

    float v[9];
#pragma unroll
    for (int t = 0; t < 9; ++t) v[t] = p[t];

    const float R3 = 1.0f/3.0f, R5 = 0.2f, R7 = 1.0f/7.0f, R9 = 1.0f/9.0f;
    const float NC = -0.5f * 1.44269504088896340736f;   // -0.5*log2(e)

    // ---- membership(x): nested sums ----
    const float s3 = v[3] + v[4] + v[5];
    const float s5 = s3 + v[2] + v[6];
    const float s7 = s5 + v[1] + v[7];
    const float s9 = s7 + v[0] + v[8];
    const float m3 = s3 * R3, m5 = s5 * R5, m7 = s7 * R7, m9 = s9 * R9;

    float kmm[5];
    kmm[0] = m7; kmm[1] = m5; kmm[2] = m3; kmm[3] = v[4]; kmm[4] = m9;

    const float v_avg = (m7 + m5 + m3 + v[4] + m9) * R5;

    // ---- omega = |x - v_avg|; var = membership(omega) + eps ----
    float w[9];
#pragma unroll
    for (int t = 0; t < 9; ++t) w[t] = fabsf(v[t] - v_avg);

    const float t3 = w[3] + w[4] + w[5];
    const float t5 = t3 + w[2] + w[6];
    const float t7 = t5 + w[1] + w[7];
    const float t9 = t7 + w[0] + w[8];
    const float var4 = t9 * R9 + EPS;        // var[...,4] (m_only_var probe)

    float c[5];                               // c_j = -0.5*log2e / var_j
    c[0] = NC * rcp_f(t7 * R7 + EPS);
    c[1] = NC * rcp_f(t5 * R5 + EPS);
    c[2] = NC * rcp_f(t3 * R3 + EPS);
    c[3] = NC * rcp_f(w[4] + EPS);
    c[4] = NC * rcp_f(var4);

    // ---- pi[j][t] = 2^(c_j * d^2); reduce over j (sum all t, max t!=4) ----
    // Exact identity: pi[3][4] = 2^(c3*0*0) = 1.0 bit-exactly, and since all
    // pi <= 1, max_pi[4] = 1.0 constant -> skip t=4 in the max chains.
    float sum_pi[9], max_pi[9];
#pragma unroll
    for (int t = 0; t < 9; ++t) { sum_pi[t] = 0.f; max_pi[t] = 0.f; }

#pragma unroll
    for (int j = 0; j < 5; ++j) {
        const float k  = kmm[j];
        const float cj = c[j];
#pragma unroll
        for (int t = 0; t < 9; ++t) {
            if (j == 3 && t == 4) {           // d = v[4]-v[4] = +-0 exactly
                sum_pi[4] += 1.0f;            // same summation slot/order
                continue;
            }
            const float d  = v[t] - k;
            const float pi = __builtin_amdgcn_exp2f(cj * d * d); // v_exp_f32
            sum_pi[t] += pi;
            if (t != 4) max_pi[t] = fmaxf(max_pi[t], pi);
        }
    }

    // thresh = min over t of max_pi[t]; max_pi[4] == 1 >= everything else,
    // so min over the other 8 is exact-identical (min is order-exact).
    float thresh = fminf(fminf(max_pi[0], max_pi[1]), max_pi[2]);
    thresh = fminf(thresh, max_pi[3]);
    thresh = fminf(fminf(thresh, max_pi[5]), max_pi[6]);
    thresh = fminf(fminf(thresh, max_pi[7]), max_pi[8]);

    float avg_pi[9];
#pragma unroll
    for (int t = 0; t < 9; ++t) avg_pi[t] = sum_pi[t] * R5;

    bool m_mem = false;
#pragma unroll
    for (int t = 0; t < 9; ++t) m_mem = m_mem || (avg_pi[t] > thresh);

    // weighted-average denoising (always computed, branchless select)
    float sn = 0.f, sd = 0.f;
#pragma unroll
    for (int t = 0; t < 9; ++t) { sn += avg_pi[t] * v[t]; sd += avg_pi[t]; }
    const float denoised = sn * rcp_f(sd);

    float res = m_mem ? m9 : ((var4 < EPS) ? v_avg : denoised);
    out[F] = res;
}

extern "C" void kernel_launch(void* const* d_in, const int* in_sizes, int n_in,
                              void* d_out, int out_size, void* d_ws, size_t ws_size,
                              hipStream_t stream) {
    (void)in_sizes; (void)n_in; (void)d_ws; (void)ws_size; (void)out_size;
    const float* x = (const float*)d_in[0];
    float* out = (float*)d_out;
    const int blocks = TOTAL / 256;       // 12288, exact
    fuzzy_pool_kernel<<<blocks, 256, 0, stream>>>(x, out);
}

// Round 5
// 162.620 us; speedup vs baseline: 1.2540x; 1.0409x over previous
//
#include <hip/hip_runtime.h>
#include <math.h>

// B,H,W,C = 4,384,384,48; KERNEL=3 -> R=Cc=128 outputs per image dim.
// TF-faithful flat view: output F=((b*128+r)*128+cc)*48+g consumes 9
// contiguous floats at row (b*384+3r+kr), offset cc*144+(g&15)*9, kr=g>>4.
// Block = (b, r, kr, cc-octet): source region = 2304 contiguous floats.
#define ROW_STRIDE 18432
#define EPS 1e-4f

static __device__ __forceinline__ float rcp_f(float a) {
    return __builtin_amdgcn_rcpf(a);      // v_rcp_f32, 1 ulp
}

__global__ __launch_bounds__(256) void fuzzy_pool_kernel(
        const float* __restrict__ x, float* __restrict__ out) {
    __shared__ float s[2304];             // 9216 B staged input

    const int tid = threadIdx.x;
    const int bid = blockIdx.x;           // ((b*128+r)*3 + kr)*8 + c8
    const int c8 = bid & 7;
    const int t1 = bid >> 3;
    const int kr = t1 % 3;                // scalar magic-mul
    const int t2 = t1 / 3;
    const int r  = t2 & 127;
    const int b  = t2 >> 7;

    const float* __restrict__ src =
        x + ((size_t)(b * 384 + 3 * r + kr) * ROW_STRIDE + c8 * 2304);

    // ---- coalesced global -> LDS staging: 576 float4, 16B/lane ----
    const float4* __restrict__ s4 = (const float4*)src;
    float4* l4 = (float4*)s;
    l4[tid]       = s4[tid];
    l4[tid + 256] = s4[tid + 256];
    if (tid < 64) l4[tid + 512] = s4[tid + 512];
    __syncthreads();

    // thread (i = cc offset 0..15, j = g' 0..15)
    const int i = tid >> 4;
    const int j = tid & 15;
    const float* __restrict__ vp = s + (i * 144 + j * 9);  // 36B lane stride:
                                                           // 2-way banks, free
    float v[9];
#pragma unroll
    for (int t = 0; t < 9; ++t) v[t] = vp[t];

    const float R3 = 1.0f/3.0f, R5 = 0.2f, R7 = 1.0f/7.0f, R9 = 1.0f/9.0f;
    const float NC = -0.5f * 1.44269504088896340736f;   // -0.5*log2(e)

    // ---- membership(x): nested sums ----
    const float s3 = v[3] + v[4] + v[5];
    const float s5 = s3 + v[2] + v[6];
    const float s7 = s5 + v[1] + v[7];
    const float s9 = s7 + v[0] + v[8];
    const float m3 = s3 * R3, m5 = s5 * R5, m7 = s7 * R7, m9 = s9 * R9;

    float kmm[5];
    kmm[0] = m7; kmm[1] = m5; kmm[2] = m3; kmm[3] = v[4]; kmm[4] = m9;

    const float v_avg = (m7 + m5 + m3 + v[4] + m9) * R5;

    // ---- omega = |x - v_avg|; var = membership(omega) + eps ----
    float w[9];
#pragma unroll
    for (int t = 0; t < 9; ++t) w[t] = fabsf(v[t] - v_avg);

    const float t3 = w[3] + w[4] + w[5];
    const float t5 = t3 + w[2] + w[6];
    const float t7 = t5 + w[1] + w[7];
    const float t9 = t7 + w[0] + w[8];
    const float var4 = t9 * R9 + EPS;        // var[...,4] (m_only_var probe)

    float c[5];                               // c_j = -0.5*log2e / var_j
    c[0] = NC * rcp_f(t7 * R7 + EPS);
    c[1] = NC * rcp_f(t5 * R5 + EPS);
    c[2] = NC * rcp_f(t3 * R3 + EPS);
    c[3] = NC * rcp_f(w[4] + EPS);
    c[4] = NC * rcp_f(var4);

    // ---- pi[jj][t] = 2^(c_jj * d^2); sum over jj all t, max over jj t!=4 ----
    // Exact: pi[3][4] = 1.0 bit-exactly; all pi <= 1 so max_pi[4] = 1.0 and
    // t=4 drops out of the thresh min-tree.
    float sum_pi[9], max_pi[9];
#pragma unroll
    for (int t = 0; t < 9; ++t) { sum_pi[t] = 0.f; max_pi[t] = 0.f; }

#pragma unroll
    for (int jj = 0; jj < 5; ++jj) {
        const float k  = kmm[jj];
        const float cj = c[jj];
#pragma unroll
        for (int t = 0; t < 9; ++t) {
            if (jj == 3 && t == 4) {          // d = v[4]-v[4] = +-0 exactly
                sum_pi[4] += 1.0f;            // same summation slot/order
                continue;
            }
            const float d  = v[t] - k;
            const float pi = __builtin_amdgcn_exp2f(cj * d * d); // v_exp_f32
            sum_pi[t] += pi;
            if (t != 4) max_pi[t] = fmaxf(max_pi[t], pi);
        }
    }

    float thresh = fminf(fminf(max_pi[0], max_pi[1]), max_pi[2]);
    thresh = fminf(thresh, max_pi[3]);
    thresh = fminf(fminf(thresh, max_pi[5]), max_pi[6]);
    thresh = fminf(fminf(thresh, max_pi[7]), max_pi[8]);

    // any_t(sum_pi[t]*0.2 > thresh)  <=>  max_t(sum_pi)*0.2 > thresh
    // (x*0.2 rounding is monotone => exact equivalence)
    float ms = fmaxf(fmaxf(sum_pi[0], sum_pi[1]), sum_pi[2]);
    ms = fmaxf(fmaxf(ms, sum_pi[3]), sum_pi[4]);
    ms = fmaxf(fmaxf(ms, sum_pi[5]), sum_pi[6]);
    ms = fmaxf(fmaxf(ms, sum_pi[7]), sum_pi[8]);
    const bool m_mem = (ms * R5) > thresh;

    // weighted-average denoising; the 0.2 factor cancels in the ratio
    float sn = 0.f, sd = 0.f;
#pragma unroll
    for (int t = 0; t < 9; ++t) { sn += sum_pi[t] * v[t]; sd += sum_pi[t]; }
    const float denoised = sn * rcp_f(sd);

    const float res = m_mem ? m9 : ((var4 < EPS) ? v_avg : denoised);

    const int cc = c8 * 16 + i;
    const int g  = kr * 16 + j;
    out[((size_t)((b * 128 + r) * 128 + cc)) * 48 + g] = res;
}

extern "C" void kernel_launch(void* const* d_in, const int* in_sizes, int n_in,
                              void* d_out, int out_size, void* d_ws, size_t ws_size,
                              hipStream_t stream) {
    (void)in_sizes; (void)n_in; (void)d_ws; (void)ws_size; (void)out_size;
    const float* x = (const float*)d_in[0];
    float* out = (float*)d_out;
    const int blocks = 4 * 128 * 3 * 8;   // (b, r, kr, cc-octet) = 12288
    fuzzy_pool_kernel<<<blocks, 256, 0, stream>>>(x, out);
}